// Round 15
// baseline (826.541 us; speedup 1.0000x reference)
//
#include <hip/hip_runtime.h>

#define NN 50000
#define NE 1600000
#define DD 64
#define NGRAPH 64
#define DOUT 32
#define DELTA_F 2.5749f
#define BN_EPS_F 1e-5f

typedef unsigned short ushort;
typedef __attribute__((ext_vector_type(8))) short short8;
typedef __attribute__((ext_vector_type(4))) float floatx4;

static __device__ __forceinline__ float blo(unsigned u) {
    return __uint_as_float(u << 16);
}
static __device__ __forceinline__ float bhi(unsigned u) {
    return __uint_as_float(u & 0xFFFF0000u);
}
static __device__ __forceinline__ ushort f2bu(float f) {
    unsigned u = __float_as_uint(f);
    unsigned r = (u + 0x7FFF + ((u >> 16) & 1)) >> 16;   // round-to-nearest-even
    return (ushort)r;
}
static __device__ __forceinline__ unsigned pk(float a, float b) {
    return ((unsigned)f2bu(b) << 16) | (unsigned)f2bu(a);
}

// ---------------- init ----------------
__global__ void k_init(int* __restrict__ counts, float* __restrict__ bnstat,
                       float* __restrict__ gpool, int* __restrict__ hist) {
    int i = blockIdx.x * 256 + threadIdx.x;
    if (i < NN) counts[i] = 0;
    if (i < 384) bnstat[i] = 0.f;
    if (i < NGRAPH * DD) gpool[i] = 0.f;
    if (i < 512) hist[i] = 0;
}

// ---------------- CSR build (rank/scan/place — single atomic pass) ----------------
__global__ void k_rank(const int* __restrict__ dst, int* __restrict__ counts,
                       int* __restrict__ rank) {
    int e = blockIdx.x * 256 + threadIdx.x;
    if (e < NE) rank[e] = atomicAdd(&counts[dst[e]], 1);
}

__global__ void k_scan_a(const int* __restrict__ counts, int* __restrict__ blockSums) {
    __shared__ int red[256];
    int tid = threadIdx.x;
    int gid = blockIdx.x * 256 + tid;
    int v = (gid < NN) ? counts[gid] : 0;
    red[tid] = v;
    __syncthreads();
    for (int s = 128; s > 0; s >>= 1) {
        if (tid < s) red[tid] += red[tid + s];
        __syncthreads();
    }
    if (tid == 0) blockSums[blockIdx.x] = red[0];
}

__global__ void k_scan_b(const int* __restrict__ blockSums, int* __restrict__ blockBase) {
    __shared__ int sh[256];
    int tid = threadIdx.x;
    int v = (tid < 196) ? blockSums[tid] : 0;
    sh[tid] = v;
    __syncthreads();
    for (int off = 1; off < 256; off <<= 1) {
        int t = (tid >= off) ? sh[tid - off] : 0;
        __syncthreads();
        sh[tid] += t;
        __syncthreads();
    }
    blockBase[tid] = sh[tid] - v;  // exclusive
}

__global__ void k_scan_c(const int* __restrict__ counts, const int* __restrict__ blockBase,
                         int* __restrict__ row_ptr) {
    __shared__ int sh[256];
    int tid = threadIdx.x;
    int gid = blockIdx.x * 256 + tid;
    int v = (gid < NN) ? counts[gid] : 0;
    sh[tid] = v;
    __syncthreads();
    for (int off = 1; off < 256; off <<= 1) {
        int t = (tid >= off) ? sh[tid - off] : 0;
        __syncthreads();
        sh[tid] += t;
        __syncthreads();
    }
    int excl = blockBase[blockIdx.x] + sh[tid] - v;
    if (gid <= NN) row_ptr[gid] = excl;
}

__global__ void k_place(const int* __restrict__ src, const int* __restrict__ dst,
                        const int* __restrict__ rank, const int* __restrict__ row_ptr,
                        int* __restrict__ csr_src) {
    int e = blockIdx.x * 256 + threadIdx.x;
    if (e < NE) csr_src[row_ptr[dst[e]] + rank[e]] = src[e];
}

// ---------------- degree-sort: histogram -> scan -> place ----------------
__global__ void k_hist(const int* __restrict__ counts, int* __restrict__ hist) {
    int i = blockIdx.x * 256 + threadIdx.x;
    if (i < NN) {
        int d = counts[i];
        if (d > 511) d = 511;
        atomicAdd(&hist[d], 1);
    }
}

__global__ void k_hscan(int* __restrict__ hist, int* __restrict__ hbase) {
    __shared__ int sh[512];
    int tid = threadIdx.x;          // 512 threads
    int v = hist[tid];
    sh[tid] = v;
    __syncthreads();
    for (int off = 1; off < 512; off <<= 1) {
        int t = (tid >= off) ? sh[tid - off] : 0;
        __syncthreads();
        sh[tid] += t;
        __syncthreads();
    }
    hbase[tid] = sh[tid] - v;       // exclusive
}

__global__ void k_permplace(const int* __restrict__ counts, int* __restrict__ hbase,
                            int* __restrict__ perm) {
    int i = blockIdx.x * 256 + threadIdx.x;
    if (i < NN) {
        int d = counts[i];
        if (d > 511) d = 511;
        int pos = atomicAdd(&hbase[d], 1);
        perm[pos] = i;
    }
}

// ---------------- weight prep ----------------
// Wb: bf16 MFMA B-fragment order (hi only). Per layer: [g 3][kb 8][t 4][lane 64][j 8]
//   value = W[o=t*16+(lane&15)][k_global = g*256 + kb*32 + (lane>>4)*8 + j]
// Wt1: f32 g=1 chunk transposed [layer][k 256][o 64]  (the cnt/DELTA-amplified chunk)
// Wsm: f32 transposed 64x64 (Lin1/Lin2).
__global__ void k_wprep(const float* __restrict__ w0, const float* __restrict__ w1,
                        const float* __restrict__ w2,
                        const float* __restrict__ a0, const float* __restrict__ a1,
                        const float* __restrict__ a2, const float* __restrict__ a3,
                        const float* __restrict__ a4, const float* __restrict__ a5,
                        ushort* __restrict__ Wb, float* __restrict__ Wt1,
                        float* __restrict__ Wsm) {
    int i = blockIdx.x * 256 + threadIdx.x;
    if (i < 3 * 49152) {
        int layer = i / 49152, r = i % 49152;
        const float* w = (layer == 0) ? w0 : ((layer == 1) ? w1 : w2);
        int g = r / 16384, r2 = r % 16384;
        int kb = r2 >> 11, r3 = r2 & 2047;
        int t = r3 >> 9, r4 = r3 & 511;
        int l = r4 >> 3, j = r4 & 7;
        int k = kb * 32 + (l >> 4) * 8 + j;
        int o = t * 16 + (l & 15);
        Wb[i] = f2bu(w[o * 768 + g * 256 + k]);
    } else if (i < 3 * 49152 + 3 * 16384) {
        int i2 = i - 3 * 49152;
        int layer = i2 / 16384, r = i2 % 16384;
        const float* w = (layer == 0) ? w0 : ((layer == 1) ? w1 : w2);
        int k = r >> 6, o = r & 63;
        Wt1[i2] = w[o * 768 + 256 + k];
    } else if (i < 3 * 49152 + 3 * 16384 + 6 * 4096) {
        int r2 = i - 3 * 49152 - 3 * 16384;
        int l = r2 >> 12, r = r2 & 4095;
        const float* w = (l == 0) ? a0 : (l == 1) ? a1 : (l == 2) ? a2
                       : (l == 3) ? a3 : (l == 4) ? a4 : a5;
        int o = r >> 6, j = r & 63;
        Wsm[l * 4096 + j * 64 + o] = w[r];
    }
}

// ---------------- x (f32) -> bf16 gather table ----------------
__global__ void k_x2h(const float* __restrict__ x, ushort* __restrict__ XH) {
    int i = blockIdx.x * 256 + threadIdx.x;
    if (i < NN * 16) {
        float4 v = *(const float4*)(x + (size_t)i * 4);
        ushort4 h;
        h.x = f2bu(v.x); h.y = f2bu(v.y); h.z = f2bu(v.z); h.w = f2bu(v.w);
        *(ushort4*)(XH + (size_t)i * 4) = h;
    }
}

// ======================================================================
// Fused layer, Ntile = 32 nodes/block, degree-sorted node assignment
// (slot -> perm[slot]); all 32 nodes of a block have ~equal degree so the
// 8-lane gather groups finish together (removes max-of-8 Poisson waste).
// Hybrid GEMM: g=1 f32 VALU; g=0,2 MFMA bf16-hi.
// Gather: 4-row double-buffered batches (compiler caps this kernel at ~64
// VGPRs and SPILLS beyond 4-row — measured R10/R14; do not deepen).
// LDS (38912 B): Af32[k192][pad34] | Ag[32][200] bf16 (overlaid by hsf).
// Biases/deg/perm live in Af32 pad cols 32/33.
// ======================================================================
#define MBIAS(i) Af32[(i) * 34 + 32]
#define B1V(i)   Af32[(64 + (i)) * 34 + 32]
#define B2V(i)   Af32[(128 + (i)) * 34 + 32]
#define DEGV(m)  Af32[(m) * 34 + 33]
#define PERMV(m) Af32[(32 + (m)) * 34 + 33]

__global__ __launch_bounds__(256, 4) void k_fused(
    const float* __restrict__ X, const ushort* __restrict__ XH,
    const int* __restrict__ row_ptr, const int* __restrict__ csr_src,
    const int* __restrict__ perm,
    const ushort* __restrict__ Wbh, const float* __restrict__ Wt1,
    const float* __restrict__ mlp_b,
    const float* __restrict__ W1t, const float* __restrict__ b1,
    const float* __restrict__ W2t, const float* __restrict__ b2,
    float* __restrict__ Y, float* __restrict__ bnstat) {
    __shared__ __align__(16) char smem[38912];
    float* const Af32 = (float*)smem;                 // 192 x 34 f32 = 26112 B
    ushort* const Ag = (ushort*)(smem + 26112);       // 32 x 200 bf16 = 12800 B
    float* const hsf = (float*)(smem + 26112);        // overlays Ag (8704 B)

    const int tid = threadIdx.x;
    const int node0 = blockIdx.x * 32;

    if (tid < 64) {
        MBIAS(tid) = mlp_b[tid];
        B1V(tid) = b1[tid];
        B2V(tid) = b2[tid];
    }

    // ---- gather: 32 groups of 8 lanes; 4-row double-buffered batches ----
    {
        const int l8 = tid & 7;
        const int m = tid >> 3;                // 0..31
        const int slot = node0 + m;
        const bool valid = slot < NN;
        const int node = valid ? perm[slot] : 0;
        const int f0 = l8 * 8;
        const ushort* Xp = XH + f0;

        float s[8], q[8], mx[8];
#pragma unroll
        for (int i = 0; i < 8; ++i) { s[i] = 0.f; q[i] = 0.f; mx[i] = -3.402823466e38f; }

        auto acc8 = [&](const uint4& rr) {
            float v0 = blo(rr.x), v1 = bhi(rr.x);
            float v2 = blo(rr.y), v3 = bhi(rr.y);
            float v4 = blo(rr.z), v5 = bhi(rr.z);
            float v6 = blo(rr.w), v7 = bhi(rr.w);
            s[0] += v0; q[0] = fmaf(v0, v0, q[0]); mx[0] = fmaxf(mx[0], v0);
            s[1] += v1; q[1] = fmaf(v1, v1, q[1]); mx[1] = fmaxf(mx[1], v1);
            s[2] += v2; q[2] = fmaf(v2, v2, q[2]); mx[2] = fmaxf(mx[2], v2);
            s[3] += v3; q[3] = fmaf(v3, v3, q[3]); mx[3] = fmaxf(mx[3], v3);
            s[4] += v4; q[4] = fmaf(v4, v4, q[4]); mx[4] = fmaxf(mx[4], v4);
            s[5] += v5; q[5] = fmaf(v5, v5, q[5]); mx[5] = fmaxf(mx[5], v5);
            s[6] += v6; q[6] = fmaf(v6, v6, q[6]); mx[6] = fmaxf(mx[6], v6);
            s[7] += v7; q[7] = fmaf(v7, v7, q[7]); mx[7] = fmaxf(mx[7], v7);
        };

        int beg = 0, end = 0;
        if (valid) { beg = row_ptr[node]; end = row_ptr[node + 1]; }
        const int deg = end - beg;
        const int nb = (deg + 3) >> 2;

        uint4 ra[4], rb[4];
        int ia[4];
        if (nb > 0) {
#pragma unroll
            for (int j = 0; j < 4; ++j) {
                int e = beg + j;
                ia[j] = csr_src[(e < end) ? e : end - 1];
            }
#pragma unroll
            for (int j = 0; j < 4; ++j)
                ra[j] = *(const uint4*)(Xp + (size_t)ia[j] * 64);
            if (nb > 1) {
#pragma unroll
                for (int j = 0; j < 4; ++j) {
                    int e = beg + 4 + j;
                    ia[j] = csr_src[(e < end) ? e : end - 1];
                }
            }
        }
        for (int t = 0; t < nb; ++t) {
            if (t + 1 < nb) {
#pragma unroll
                for (int j = 0; j < 4; ++j)
                    rb[j] = *(const uint4*)(Xp + (size_t)ia[j] * 64);
            }
            if (t + 2 < nb) {
                int b2e = beg + (t + 2) * 4;
#pragma unroll
                for (int j = 0; j < 4; ++j) {
                    int e = b2e + j;
                    ia[j] = csr_src[(e < end) ? e : end - 1];
                }
            }
            int cnt = end - (beg + t * 4);
            if (cnt >= 4) {
#pragma unroll
                for (int j = 0; j < 4; ++j) acc8(ra[j]);
            } else {
#pragma unroll
                for (int j = 0; j < 4; ++j) if (j < cnt) acc8(ra[j]);
            }
            if (t + 1 < nb) {
#pragma unroll
                for (int j = 0; j < 4; ++j) ra[j] = rb[j];
            }
        }

        float cdeg = valid ? (float)deg : 1.f;
        float rc = 1.0f / cdeg;
        float var[8];
#pragma unroll
        for (int i = 0; i < 8; ++i) {
            float mean = s[i] * rc;
            var[i] = fmaxf(q[i] * rc - mean * mean, 0.f);
            if (!valid) { mx[i] = 0.f; var[i] = 0.f; }
        }
        // f32 stats (for the VALU g=1 GEMM): [k][n] stride 34, cols 0..31
#pragma unroll
        for (int i = 0; i < 8; ++i) {
            Af32[(f0 + i) * 34 + m] = s[i];
            Af32[(64 + f0 + i) * 34 + m] = mx[i];
            Af32[(128 + f0 + i) * 34 + m] = var[i];
        }
        // bf16-hi stats (for the MFMA g=0,2 GEMM): [m][k] pitch 200
        uint4 hv;
        hv.x = pk(s[0], s[1]); hv.y = pk(s[2], s[3]);
        hv.z = pk(s[4], s[5]); hv.w = pk(s[6], s[7]);
        *(uint4*)&Ag[m * 200 + f0] = hv;
        hv.x = pk(mx[0], mx[1]); hv.y = pk(mx[2], mx[3]);
        hv.z = pk(mx[4], mx[5]); hv.w = pk(mx[6], mx[7]);
        *(uint4*)&Ag[m * 200 + 64 + f0] = hv;
        hv.x = pk(var[0], var[1]); hv.y = pk(var[2], var[3]);
        hv.z = pk(var[4], var[5]); hv.w = pk(var[6], var[7]);
        *(uint4*)&Ag[m * 200 + 128 + f0] = hv;
        if (l8 == 0) {
            DEGV(m) = cdeg;
            PERMV(m) = __int_as_float(node);
        }
    }
    __syncthreads();

    // ---- load MFMA A fragments (then Ag is dead; hsf overlays it) ----
    const int ln = tid & 63, wvi = tid >> 6;
    const int quad = ln >> 4, l16 = ln & 15;
    const int mtile = wvi >> 1;          // 0..1
    const int nt0 = (wvi & 1) * 2;       // ntiles nt0, nt0+1

    const ushort* Arow = Ag + (mtile * 16 + l16) * 200 + quad * 8;
    short8 afh[6];
    afh[0] = *(const short8*)(Arow + 0);    // s    k 0..31
    afh[1] = *(const short8*)(Arow + 32);   // s    k 32..63
    afh[2] = *(const short8*)(Arow + 64);   // max  k 0..31
    afh[3] = *(const short8*)(Arow + 96);   // max  k 32..63
    afh[4] = *(const short8*)(Arow + 128);  // var  k 0..31
    afh[5] = *(const short8*)(Arow + 160);  // var  k 32..63
    __syncthreads();   // all frag loads done -> hsf region free

    // ---- MFMA: g=0 and g=2 chunks, bf16-hi ----
    floatx4 accA[2][2], accB[2][2];
#pragma unroll
    for (int gi = 0; gi < 2; ++gi)
#pragma unroll
        for (int n = 0; n < 2; ++n) {
            accA[gi][n] = (floatx4){0.f, 0.f, 0.f, 0.f};
            accB[gi][n] = (floatx4){0.f, 0.f, 0.f, 0.f};
        }
#pragma unroll
    for (int gi = 0; gi < 2; ++gi) {
        const int g = gi * 2;
#pragma unroll
        for (int kb = 0; kb < 8; ++kb) {
            const int am = (kb < 4) ? kb : ((kb < 6) ? (kb - 4) : (kb - 2));
            const int boff = (((g * 8 + kb) * 4 + nt0) * 512) + ln * 8;
            short8 bh0 = *(const short8*)(Wbh + boff);
            short8 bh1 = *(const short8*)(Wbh + boff + 512);
            if (kb == 4 || kb == 5) {
                accB[gi][0] = __builtin_amdgcn_mfma_f32_16x16x32_bf16(afh[am], bh0, accB[gi][0], 0, 0, 0);
                accB[gi][1] = __builtin_amdgcn_mfma_f32_16x16x32_bf16(afh[am], bh1, accB[gi][1], 0, 0, 0);
            } else {
                accA[gi][0] = __builtin_amdgcn_mfma_f32_16x16x32_bf16(afh[am], bh0, accA[gi][0], 0, 0, 0);
                accA[gi][1] = __builtin_amdgcn_mfma_f32_16x16x32_bf16(afh[am], bh1, accA[gi][1], 0, 0, 0);
            }
        }
    }
    // MFMA partial (scales for g=0: 1 and 1/c; g=2: D/c and D/c^2) -> hsf[n][m]
#pragma unroll
    for (int r = 0; r < 4; ++r) {
        int m = mtile * 16 + quad * 4 + r;
        float dg = DEGV(m), rcd = 1.f / dg;
        float cA2 = DELTA_F * rcd;
        float cB2 = DELTA_F * rcd * rcd;
#pragma unroll
        for (int nt = 0; nt < 2; ++nt) {
            int n = (nt0 + nt) * 16 + l16;
            hsf[n * 34 + m] = accA[0][nt][r] + cA2 * accA[1][nt][r]
                            + rcd * accB[0][nt][r] + cB2 * accB[1][nt][r];
        }
    }

    // ---- f32 VALU GEMM for g=1 chunk (amplified by cnt/DELTA) ----
    const int tx = tid & 15, ty = tid >> 4;
    const int o0 = tx * 4, n0 = ty * 2;
    const float2* const Af2 = (const float2*)Af32;   // stride 17 float2

    float A1[8], B1[8];
#pragma unroll
    for (int i = 0; i < 8; ++i) { A1[i] = 0.f; B1[i] = 0.f; }
#pragma unroll 4
    for (int k = 0; k < 128; ++k) {          // s rows(0..63) + max rows(64..127)
        float2 a = Af2[k * 17 + ty];
        const float4 w = *(const float4*)(Wt1 + k * 64 + o0);
        A1[0] += a.x * w.x; A1[1] += a.x * w.y; A1[2] += a.x * w.z; A1[3] += a.x * w.w;
        A1[4] += a.y * w.x; A1[5] += a.y * w.y; A1[6] += a.y * w.z; A1[7] += a.y * w.w;
    }
#pragma unroll 4
    for (int k = 0; k < 64; ++k) {           // var rows x W rows 192..255
        float2 a = Af2[(128 + k) * 17 + ty];
        const float4 w = *(const float4*)(Wt1 + (192 + k) * 64 + o0);
        A1[0] += a.x * w.x; A1[1] += a.x * w.y; A1[2] += a.x * w.z; A1[3] += a.x * w.w;
        A1[4] += a.y * w.x; A1[5] += a.y * w.y; A1[6] += a.y * w.z; A1[7] += a.y * w.w;
    }
#pragma unroll 4
    for (int k = 0; k < 64; ++k) {           // mean fold: s rows x W rows 128..191
        float2 a = Af2[k * 17 + ty];
        const float4 w = *(const float4*)(Wt1 + (128 + k) * 64 + o0);
        B1[0] += a.x * w.x; B1[1] += a.x * w.y; B1[2] += a.x * w.z; B1[3] += a.x * w.w;
        B1[4] += a.y * w.x; B1[5] += a.y * w.y; B1[6] += a.y * w.z; B1[7] += a.y * w.w;
    }
    __syncthreads();   // all MFMA partials in hsf

    // ---- combine: h = partial + (c/D)*A1 + (1/D)*B1 + x + bias ----
#pragma unroll
    for (int ni = 0; ni < 2; ++ni) {
        int n = n0 + ni;
        int slot = node0 + n;
        int node = __float_as_int(PERMV(n));
        float dg = DEGV(n);
        float cA1 = dg * (1.0f / DELTA_F);
        const float cB1 = (1.0f / DELTA_F);
        float4 xv = make_float4(0.f, 0.f, 0.f, 0.f);
        if (slot < NN) xv = *(const float4*)(X + (size_t)node * DD + o0);
#pragma unroll
        for (int oi = 0; oi < 4; ++oi) {
            int idx = (o0 + oi) * 34 + n;
            float xa = (oi == 0) ? xv.x : (oi == 1) ? xv.y : (oi == 2) ? xv.z : xv.w;
            hsf[idx] = hsf[idx] + cA1 * A1[ni * 4 + oi] + cB1 * B1[ni * 4 + oi]
                     + xa + MBIAS(o0 + oi);
        }
    }
    __syncthreads();

    // ---- Lin1 (f32): stream W1t from global, h-pairs from LDS ----
    const float2* const hs2 = (const float2*)hsf;
    float l1[8];
#pragma unroll
    for (int i = 0; i < 8; ++i) l1[i] = 0.f;
#pragma unroll 4
    for (int j = 0; j < 64; ++j) {
        float2 a = hs2[j * 17 + ty];
        const float4 wv4 = *(const float4*)(W1t + j * 64 + o0);
        l1[0] += a.x * wv4.x; l1[1] += a.x * wv4.y; l1[2] += a.x * wv4.z; l1[3] += a.x * wv4.w;
        l1[4] += a.y * wv4.x; l1[5] += a.y * wv4.y; l1[6] += a.y * wv4.z; l1[7] += a.y * wv4.w;
    }
    __syncthreads();
#pragma unroll
    for (int ni = 0; ni < 2; ++ni)
#pragma unroll
        for (int oi = 0; oi < 4; ++oi)
            hsf[(o0 + oi) * 34 + n0 + ni] = fmaxf(l1[ni * 4 + oi] + B1V(o0 + oi), 0.f);
    __syncthreads();

    // ---- Lin2 + outer relu ----
    float l2[8];
#pragma unroll
    for (int i = 0; i < 8; ++i) l2[i] = 0.f;
#pragma unroll 4
    for (int j = 0; j < 64; ++j) {
        float2 a = hs2[j * 17 + ty];
        const float4 wv4 = *(const float4*)(W2t + j * 64 + o0);
        l2[0] += a.x * wv4.x; l2[1] += a.x * wv4.y; l2[2] += a.x * wv4.z; l2[3] += a.x * wv4.w;
        l2[4] += a.y * wv4.x; l2[5] += a.y * wv4.y; l2[6] += a.y * wv4.z; l2[7] += a.y * wv4.w;
    }
    __syncthreads();
#pragma unroll
    for (int ni = 0; ni < 2; ++ni) {
        int slot = node0 + n0 + ni;
        int node = __float_as_int(PERMV(n0 + ni));
        float4 yv;
        yv.x = fmaxf(l2[ni * 4 + 0] + B2V(o0 + 0), 0.f);
        yv.y = fmaxf(l2[ni * 4 + 1] + B2V(o0 + 1), 0.f);
        yv.z = fmaxf(l2[ni * 4 + 2] + B2V(o0 + 2), 0.f);
        yv.w = fmaxf(l2[ni * 4 + 3] + B2V(o0 + 3), 0.f);
        if (slot < NN) *(float4*)(Y + (size_t)node * DD + o0) = yv;
        hsf[(o0 + 0) * 34 + n0 + ni] = yv.x;
        hsf[(o0 + 1) * 34 + n0 + ni] = yv.y;
        hsf[(o0 + 2) * 34 + n0 + ni] = yv.z;
        hsf[(o0 + 3) * 34 + n0 + ni] = yv.w;
    }
    __syncthreads();

    // ---- BN partial sums (columns n <-> slots node0+n, contiguous) ----
    if (tid < 64) {
        float s = 0.f, sq = 0.f;
        int lim = NN - node0;
        if (lim > 32) lim = 32;
        for (int n = 0; n < lim; ++n) {
            float v = hsf[tid * 34 + n];
            s += v;
            sq += v * v;
        }
        atomicAdd(&bnstat[tid], s);
        atomicAdd(&bnstat[64 + tid], sq);
    }
}

// ---------------- BN finalize+apply (+bf16 table write, + fused pool) ----------------
__global__ __launch_bounds__(256) void k_bnapply(
    const float* __restrict__ Y, const float* __restrict__ bs,
    const float* __restrict__ g, const float* __restrict__ b,
    float* __restrict__ XO, ushort* __restrict__ XH,
    const int* __restrict__ batch, float* __restrict__ gpool, int do_pool) {
    __shared__ float sc[64], shf[64], pool[512];
    int tid = threadIdx.x;
    if (tid < 64) {
        float mean = bs[tid] * (1.f / NN);
        float var = fmaxf(bs[64 + tid] * (1.f / NN) - mean * mean, 0.f);
        float inv = rsqrtf(var + BN_EPS_F);
        float s = g[tid] * inv;
        sc[tid] = s;
        shf[tid] = b[tid] - mean * s;
    }
    __syncthreads();
    int i = blockIdx.x * 256 + tid;  // float4 index
    int n = i >> 4, fq = (i & 15) * 4;
    float4 r = make_float4(0.f, 0.f, 0.f, 0.f);
    bool valid = i < NN * 16;
    if (valid) {
        float4 y = *(const float4*)(Y + (size_t)i * 4);
        r.x = y.x * sc[fq + 0] + shf[fq + 0];
        r.y = y.y * sc[fq + 1] + shf[fq + 1];
        r.z = y.z * sc[fq + 2] + shf[fq + 2];
        r.w = y.w * sc[fq + 3] + shf[fq + 3];
        *(float4*)(XO + (size_t)i * 4) = r;
        ushort4 h;
        h.x = f2bu(r.x); h.y = f2bu(r.y); h.z = f2bu(r.z); h.w = f2bu(r.w);
        *(ushort4*)(XH + (size_t)i * 4) = h;
    }
    if (do_pool) {
        int nfirst = blockIdx.x * 16;
        int nlast = nfirst + 15;
        if (nlast >= NN) nlast = NN - 1;
        int gmin = batch[nfirst], gmax = batch[nlast];
        int span = gmax - gmin + 1;
        if (span <= 8) {
            for (int j = tid; j < span * 64; j += 256) pool[j] = 0.f;
            __syncthreads();
            if (valid) {
                int gb = batch[n] - gmin;
                atomicAdd(&pool[gb * 64 + fq + 0], r.x);
                atomicAdd(&pool[gb * 64 + fq + 1], r.y);
                atomicAdd(&pool[gb * 64 + fq + 2], r.z);
                atomicAdd(&pool[gb * 64 + fq + 3], r.w);
            }
            __syncthreads();
            for (int j = tid; j < span * 64; j += 256)
                atomicAdd(&gpool[(size_t)(gmin + (j >> 6)) * 64 + (j & 63)], pool[j]);
        } else {
            if (valid) {
                float* gp = gpool + (size_t)batch[n] * DD + fq;
                atomicAdd(gp + 0, r.x);
                atomicAdd(gp + 1, r.y);
                atomicAdd(gp + 2, r.z);
                atomicAdd(gp + 3, r.w);
            }
        }
    }
}

// ---------------- head: fc1+relu, fc2, log_softmax ----------------
__global__ __launch_bounds__(256) void k_head(const float* __restrict__ gpool,
                                              const float* __restrict__ fc1W, const float* __restrict__ fc1b,
                                              const float* __restrict__ fc2W, const float* __restrict__ fc2b,
                                              float* __restrict__ out) {
    __shared__ float sh[12576];
    float* const gs = sh;
    float* const w1t = sh + 4096;
    float* const z1s = sh + 8256;
    float* const b1s = sh + 12416;
    float* const b2s = sh + 12480;
    float* const w2t = sh;
    float* const z2s = sh + 4096;

    int tid = threadIdx.x;
    for (int i = tid; i < 4096; i += 256) {
        gs[i] = gpool[i];
        int o = i >> 6, j = i & 63;
        w1t[j * 65 + o] = fc1W[i];
    }
    if (tid < 64) b1s[tid] = fc1b[tid];
    if (tid < 32) b2s[tid] = fc2b[tid];
    __syncthreads();
    {
        int tx = tid & 15, ty = tid >> 4, o0 = tx * 4, g0 = ty * 4;
        float acc[16];
#pragma unroll
        for (int i = 0; i < 16; ++i) acc[i] = 0.f;
        for (int j = 0; j < 64; ++j) {
            float w0 = w1t[j * 65 + o0 + 0], w1 = w1t[j * 65 + o0 + 1];
            float w2 = w1t[j * 65 + o0 + 2], w3 = w1t[j * 65 + o0 + 3];
#pragma unroll
            for (int gi = 0; gi < 4; ++gi) {
                float a = gs[(g0 + gi) * 64 + j];
                acc[gi * 4 + 0] += a * w0; acc[gi * 4 + 1] += a * w1;
                acc[gi * 4 + 2] += a * w2; acc[gi * 4 + 3] += a * w3;
            }
        }
        __syncthreads();
#pragma unroll
        for (int gi = 0; gi < 4; ++gi)
#pragma unroll
            for (int oi = 0; oi < 4; ++oi)
                z1s[(g0 + gi) * 65 + o0 + oi] = fmaxf(acc[gi * 4 + oi] + b1s[o0 + oi], 0.f);
    }
    for (int i = tid; i < 2048; i += 256) {
        int o = i >> 6, j = i & 63;
        w2t[j * 33 + o] = fc2W[i];
    }
    __syncthreads();
    {
        int tx = tid & 7, ty = tid >> 3, o0 = tx * 4, g0 = ty * 2;
        float acc[8];
#pragma unroll
        for (int i = 0; i < 8; ++i) acc[i] = 0.f;
        for (int j = 0; j < 64; ++j) {
            float w0 = w2t[j * 33 + o0 + 0], w1 = w2t[j * 33 + o0 + 1];
            float w2 = w2t[j * 33 + o0 + 2], w3 = w2t[j * 33 + o0 + 3];
            float a0 = z1s[(g0 + 0) * 65 + j];
            float a1 = z1s[(g0 + 1) * 65 + j];
            acc[0] += a0 * w0; acc[1] += a0 * w1; acc[2] += a0 * w2; acc[3] += a0 * w3;
            acc[4] += a1 * w0; acc[5] += a1 * w1; acc[6] += a1 * w2; acc[7] += a1 * w3;
        }
#pragma unroll
        for (int gi = 0; gi < 2; ++gi)
#pragma unroll
            for (int oi = 0; oi < 4; ++oi)
                z2s[(g0 + gi) * 33 + o0 + oi] = acc[gi * 4 + oi] + b2s[o0 + oi];
    }
    __syncthreads();
    if (tid < 64) {
        float m = -3.402823466e38f;
        for (int c = 0; c < DOUT; ++c) m = fmaxf(m, z2s[tid * 33 + c]);
        float s = 0.f;
        for (int c = 0; c < DOUT; ++c) s += expf(z2s[tid * 33 + c] - m);
        float lse = m + logf(s);
        for (int c = 0; c < DOUT; ++c)
            out[tid * DOUT + c] = z2s[tid * 33 + c] - lse;
    }
}

extern "C" void kernel_launch(void* const* d_in, const int* in_sizes, int n_in,
                              void* d_out, int out_size, void* d_ws, size_t ws_size,
                              hipStream_t stream) {
    const float* x = (const float*)d_in[0];
    const int* ei = (const int*)d_in[1];
    const int* src = ei;
    const int* dst = ei + NE;
    const int* batch = (const int*)d_in[2];
    const float *mlpW[3], *mlpB[3], *w1[3], *bb1[3], *w2[3], *bb2[3], *bng[3], *bnb[3];
    for (int l = 0; l < 3; ++l) {
        mlpW[l] = (const float*)d_in[3 + 6 * l];
        mlpB[l] = (const float*)d_in[4 + 6 * l];
        w1[l]   = (const float*)d_in[5 + 6 * l];
        bb1[l]  = (const float*)d_in[6 + 6 * l];
        w2[l]   = (const float*)d_in[7 + 6 * l];
        bb2[l]  = (const float*)d_in[8 + 6 * l];
        bng[l]  = (const float*)d_in[21 + 2 * l];
        bnb[l]  = (const float*)d_in[22 + 2 * l];
    }
    const float* fc1W = (const float*)d_in[27];
    const float* fc1b = (const float*)d_in[28];
    const float* fc2W = (const float*)d_in[29];
    const float* fc2b = (const float*)d_in[30];
    float* out = (float*)d_out;

    char* ws = (char*)d_ws;
    size_t off = 0;
    auto alloc = [&](size_t bytes) -> void* {
        void* p = ws + off;
        off = (off + bytes + 511) & ~(size_t)511;
        return p;
    };
    int* counts    = (int*)alloc((size_t)NN * 4);
    int* row_ptr   = (int*)alloc((size_t)(NN + 1) * 4);
    int* rank      = (int*)alloc((size_t)NE * 4);
    int* blockSums = (int*)alloc(256 * 4);
    int* blockBase = (int*)alloc(256 * 4);
    int* hist      = (int*)alloc(512 * 4);
    int* hbase     = (int*)alloc(512 * 4);
    int* perm      = (int*)alloc((size_t)NN * 4);
    int* csr_src   = (int*)alloc((size_t)NE * 4);
    float* XB      = (float*)alloc((size_t)NN * DD * 4);
    float* Yb      = (float*)alloc((size_t)NN * DD * 4);
    ushort* XH     = (ushort*)alloc((size_t)NN * DD * 2);
    ushort* Wb     = (ushort*)alloc((size_t)3 * 49152 * 2);
    float* Wt1     = (float*)alloc((size_t)3 * 16384 * 4);
    float* Wsm     = (float*)alloc((size_t)6 * 4096 * 4);
    float* bnstat  = (float*)alloc(384 * 4);
    float* gpool   = (float*)alloc((size_t)NGRAPH * DD * 4);
    (void)ws_size; (void)in_sizes; (void)n_in; (void)out_size;

    k_init<<<196, 256, 0, stream>>>(counts, bnstat, gpool, hist);
    k_rank<<<6250, 256, 0, stream>>>(dst, counts, rank);
    k_hist<<<196, 256, 0, stream>>>(counts, hist);
    k_hscan<<<1, 512, 0, stream>>>(hist, hbase);
    k_permplace<<<196, 256, 0, stream>>>(counts, hbase, perm);
    k_scan_a<<<196, 256, 0, stream>>>(counts, blockSums);
    k_scan_b<<<1, 256, 0, stream>>>(blockSums, blockBase);
    k_scan_c<<<196, 256, 0, stream>>>(counts, blockBase, row_ptr);
    k_place<<<6250, 256, 0, stream>>>(src, dst, rank, row_ptr, csr_src);
    k_wprep<<<864, 256, 0, stream>>>(mlpW[0], mlpW[1], mlpW[2],
                                     w1[0], w2[0], w1[1], w2[1], w1[2], w2[2],
                                     Wb, Wt1, Wsm);
    k_x2h<<<3125, 256, 0, stream>>>(x, XH);

    const float* Xin = x;
    for (int l = 0; l < 3; ++l) {
        k_fused<<<1563, 256, 0, stream>>>(Xin, XH, row_ptr, csr_src, perm,
                                          Wb + (size_t)l * 49152,
                                          Wt1 + (size_t)l * 16384,
                                          mlpB[l],
                                          Wsm + (size_t)(2 * l) * 4096, bb1[l],
                                          Wsm + (size_t)(2 * l + 1) * 4096, bb2[l],
                                          Yb, bnstat + l * 128);
        k_bnapply<<<3125, 256, 0, stream>>>(Yb, bnstat + l * 128, bng[l], bnb[l],
                                            XB, XH, batch, gpool, (l == 2) ? 1 : 0);
        Xin = XB;
    }
    k_head<<<1, 256, 0, stream>>>(gpool, fc1W, fc1b, fc2W, fc2b, out);
}

// Round 16
// 638.992 us; speedup vs baseline: 1.2935x; 1.2935x over previous
//
#include <hip/hip_runtime.h>

#define NN 50000
#define NE 1600000
#define DD 64
#define NGRAPH 64
#define DOUT 32
#define DELTA_F 2.5749f
#define BN_EPS_F 1e-5f

typedef unsigned short ushort;
typedef __attribute__((ext_vector_type(8))) short short8;
typedef __attribute__((ext_vector_type(4))) float floatx4;

static __device__ __forceinline__ float blo(unsigned u) {
    return __uint_as_float(u << 16);
}
static __device__ __forceinline__ float bhi(unsigned u) {
    return __uint_as_float(u & 0xFFFF0000u);
}
static __device__ __forceinline__ float bu2f(ushort u) {
    return __uint_as_float(((unsigned)u) << 16);
}
static __device__ __forceinline__ ushort f2bu(float f) {
    unsigned u = __float_as_uint(f);
    unsigned r = (u + 0x7FFF + ((u >> 16) & 1)) >> 16;   // round-to-nearest-even
    return (ushort)r;
}
static __device__ __forceinline__ unsigned pk(float a, float b) {
    return ((unsigned)f2bu(b) << 16) | (unsigned)f2bu(a);
}

// ---------------- init ----------------
__global__ void k_init(int* __restrict__ counts, float* __restrict__ bnstat,
                       float* __restrict__ gpool) {
    int i = blockIdx.x * 256 + threadIdx.x;
    if (i < NN) counts[i] = 0;
    if (i < 384) bnstat[i] = 0.f;
    if (i < NGRAPH * DD) gpool[i] = 0.f;
}

// ---------------- CSR build (rank/scan/place — single atomic pass) ----------------
__global__ void k_rank(const int* __restrict__ dst, int* __restrict__ counts,
                       int* __restrict__ rank) {
    int e = blockIdx.x * 256 + threadIdx.x;
    if (e < NE) rank[e] = atomicAdd(&counts[dst[e]], 1);
}

__global__ void k_scan_a(const int* __restrict__ counts, int* __restrict__ blockSums) {
    __shared__ int red[256];
    int tid = threadIdx.x;
    int gid = blockIdx.x * 256 + tid;
    int v = (gid < NN) ? counts[gid] : 0;
    red[tid] = v;
    __syncthreads();
    for (int s = 128; s > 0; s >>= 1) {
        if (tid < s) red[tid] += red[tid + s];
        __syncthreads();
    }
    if (tid == 0) blockSums[blockIdx.x] = red[0];
}

__global__ void k_scan_b(const int* __restrict__ blockSums, int* __restrict__ blockBase) {
    __shared__ int sh[256];
    int tid = threadIdx.x;
    int v = (tid < 196) ? blockSums[tid] : 0;
    sh[tid] = v;
    __syncthreads();
    for (int off = 1; off < 256; off <<= 1) {
        int t = (tid >= off) ? sh[tid - off] : 0;
        __syncthreads();
        sh[tid] += t;
        __syncthreads();
    }
    blockBase[tid] = sh[tid] - v;  // exclusive
}

__global__ void k_scan_c(const int* __restrict__ counts, const int* __restrict__ blockBase,
                         int* __restrict__ row_ptr) {
    __shared__ int sh[256];
    int tid = threadIdx.x;
    int gid = blockIdx.x * 256 + tid;
    int v = (gid < NN) ? counts[gid] : 0;
    sh[tid] = v;
    __syncthreads();
    for (int off = 1; off < 256; off <<= 1) {
        int t = (tid >= off) ? sh[tid - off] : 0;
        __syncthreads();
        sh[tid] += t;
        __syncthreads();
    }
    int excl = blockBase[blockIdx.x] + sh[tid] - v;
    if (gid <= NN) row_ptr[gid] = excl;
}

__global__ void k_place(const int* __restrict__ src, const int* __restrict__ dst,
                        const int* __restrict__ rank, const int* __restrict__ row_ptr,
                        int* __restrict__ csr_src) {
    int e = blockIdx.x * 256 + threadIdx.x;
    if (e < NE) csr_src[row_ptr[dst[e]] + rank[e]] = src[e];
}

// ---------------- weight prep ----------------
// Wb: bf16 MFMA B-fragment order (hi only). Per layer: [g 3][kb 8][t 4][lane 64][j 8]
//   value = W[o=t*16+(lane&15)][k_global = g*256 + kb*32 + (lane>>4)*8 + j]
// Wt1: f32 g=1 chunk transposed [layer][k 256][o 64]  (the cnt/DELTA-amplified chunk)
// Wsm: f32 transposed 64x64 (Lin1/Lin2).
__global__ void k_wprep(const float* __restrict__ w0, const float* __restrict__ w1,
                        const float* __restrict__ w2,
                        const float* __restrict__ a0, const float* __restrict__ a1,
                        const float* __restrict__ a2, const float* __restrict__ a3,
                        const float* __restrict__ a4, const float* __restrict__ a5,
                        ushort* __restrict__ Wb, float* __restrict__ Wt1,
                        float* __restrict__ Wsm) {
    int i = blockIdx.x * 256 + threadIdx.x;
    if (i < 3 * 49152) {
        int layer = i / 49152, r = i % 49152;
        const float* w = (layer == 0) ? w0 : ((layer == 1) ? w1 : w2);
        int g = r / 16384, r2 = r % 16384;
        int kb = r2 >> 11, r3 = r2 & 2047;
        int t = r3 >> 9, r4 = r3 & 511;
        int l = r4 >> 3, j = r4 & 7;
        int k = kb * 32 + (l >> 4) * 8 + j;
        int o = t * 16 + (l & 15);
        Wb[i] = f2bu(w[o * 768 + g * 256 + k]);
    } else if (i < 3 * 49152 + 3 * 16384) {
        int i2 = i - 3 * 49152;
        int layer = i2 / 16384, r = i2 % 16384;
        const float* w = (layer == 0) ? w0 : ((layer == 1) ? w1 : w2);
        int k = r >> 6, o = r & 63;
        Wt1[i2] = w[o * 768 + 256 + k];
    } else if (i < 3 * 49152 + 3 * 16384 + 6 * 4096) {
        int r2 = i - 3 * 49152 - 3 * 16384;
        int l = r2 >> 12, r = r2 & 4095;
        const float* w = (l == 0) ? a0 : (l == 1) ? a1 : (l == 2) ? a2
                       : (l == 3) ? a3 : (l == 4) ? a4 : a5;
        int o = r >> 6, j = r & 63;
        Wsm[l * 4096 + j * 64 + o] = w[r];
    }
}

// ---------------- x (f32) -> bf16 gather table ----------------
__global__ void k_x2h(const float* __restrict__ x, ushort* __restrict__ XH) {
    int i = blockIdx.x * 256 + threadIdx.x;
    if (i < NN * 16) {
        float4 v = *(const float4*)(x + (size_t)i * 4);
        ushort4 h;
        h.x = f2bu(v.x); h.y = f2bu(v.y); h.z = f2bu(v.z); h.w = f2bu(v.w);
        *(ushort4*)(XH + (size_t)i * 4) = h;
    }
}

// ======================================================================
// Fused layer, Ntile = 32 nodes/block.  Hybrid GEMM:
//   g=1 (cnt/DELTA-amplified chunk): f32 VALU from f32 stats (error-critical)
//   g=0,2 (scales 1, DELTA/cnt):     MFMA bf16-hi (error ≤ ~0.1 at output)
// Gather: 4-row double-buffered batches (compiler caps this kernel at ~64
//   VGPRs and SPILLS beyond 4-row — measured R10/R14; do not deepen).
// Residual x read from bf16 XH (error ≤0.004 vs bf16-gather error ~1.0).
// LDS (38912 B): Af32[k192][pad34] | Ag[32][200] bf16 (overlaid by hsf).
// Biases/degs live in Af32 pad cols 32/33.
// ======================================================================
#define MBIAS(i) Af32[(i) * 34 + 32]
#define B1V(i)   Af32[(64 + (i)) * 34 + 32]
#define B2V(i)   Af32[(128 + (i)) * 34 + 32]
#define DEGV(m)  Af32[(m) * 34 + 33]

__global__ __launch_bounds__(256, 4) void k_fused(
    const ushort* __restrict__ XH,
    const int* __restrict__ row_ptr, const int* __restrict__ csr_src,
    const ushort* __restrict__ Wbh, const float* __restrict__ Wt1,
    const float* __restrict__ mlp_b,
    const float* __restrict__ W1t, const float* __restrict__ b1,
    const float* __restrict__ W2t, const float* __restrict__ b2,
    float* __restrict__ Y, float* __restrict__ bnstat) {
    __shared__ __align__(16) char smem[38912];
    float* const Af32 = (float*)smem;                 // 192 x 34 f32 = 26112 B
    ushort* const Ag = (ushort*)(smem + 26112);       // 32 x 200 bf16 = 12800 B
    float* const hsf = (float*)(smem + 26112);        // overlays Ag (8704 B)

    const int tid = threadIdx.x;
    const int node0 = blockIdx.x * 32;

    if (tid < 64) {
        MBIAS(tid) = mlp_b[tid];
        B1V(tid) = b1[tid];
        B2V(tid) = b2[tid];
    }

    // ---- gather: 32 groups of 8 lanes; 4-row double-buffered batches ----
    {
        const int l8 = tid & 7;
        const int m = tid >> 3;                // 0..31
        const int node = node0 + m;
        const int f0 = l8 * 8;
        const ushort* Xp = XH + f0;

        float s[8], q[8], mx[8];
#pragma unroll
        for (int i = 0; i < 8; ++i) { s[i] = 0.f; q[i] = 0.f; mx[i] = -3.402823466e38f; }

        auto acc8 = [&](const uint4& rr) {
            float v0 = blo(rr.x), v1 = bhi(rr.x);
            float v2 = blo(rr.y), v3 = bhi(rr.y);
            float v4 = blo(rr.z), v5 = bhi(rr.z);
            float v6 = blo(rr.w), v7 = bhi(rr.w);
            s[0] += v0; q[0] = fmaf(v0, v0, q[0]); mx[0] = fmaxf(mx[0], v0);
            s[1] += v1; q[1] = fmaf(v1, v1, q[1]); mx[1] = fmaxf(mx[1], v1);
            s[2] += v2; q[2] = fmaf(v2, v2, q[2]); mx[2] = fmaxf(mx[2], v2);
            s[3] += v3; q[3] = fmaf(v3, v3, q[3]); mx[3] = fmaxf(mx[3], v3);
            s[4] += v4; q[4] = fmaf(v4, v4, q[4]); mx[4] = fmaxf(mx[4], v4);
            s[5] += v5; q[5] = fmaf(v5, v5, q[5]); mx[5] = fmaxf(mx[5], v5);
            s[6] += v6; q[6] = fmaf(v6, v6, q[6]); mx[6] = fmaxf(mx[6], v6);
            s[7] += v7; q[7] = fmaf(v7, v7, q[7]); mx[7] = fmaxf(mx[7], v7);
        };

        int beg = 0, end = 0;
        if (node < NN) { beg = row_ptr[node]; end = row_ptr[node + 1]; }
        const int deg = end - beg;
        const int nb = (deg + 3) >> 2;

        uint4 ra[4], rb[4];
        int ia[4];
        if (nb > 0) {
#pragma unroll
            for (int j = 0; j < 4; ++j) {
                int e = beg + j;
                ia[j] = csr_src[(e < end) ? e : end - 1];
            }
#pragma unroll
            for (int j = 0; j < 4; ++j)
                ra[j] = *(const uint4*)(Xp + (size_t)ia[j] * 64);
            if (nb > 1) {
#pragma unroll
                for (int j = 0; j < 4; ++j) {
                    int e = beg + 4 + j;
                    ia[j] = csr_src[(e < end) ? e : end - 1];
                }
            }
        }
        for (int t = 0; t < nb; ++t) {
            if (t + 1 < nb) {
#pragma unroll
                for (int j = 0; j < 4; ++j)
                    rb[j] = *(const uint4*)(Xp + (size_t)ia[j] * 64);
            }
            if (t + 2 < nb) {
                int b2e = beg + (t + 2) * 4;
#pragma unroll
                for (int j = 0; j < 4; ++j) {
                    int e = b2e + j;
                    ia[j] = csr_src[(e < end) ? e : end - 1];
                }
            }
            int cnt = end - (beg + t * 4);
            if (cnt >= 4) {
#pragma unroll
                for (int j = 0; j < 4; ++j) acc8(ra[j]);
            } else {
#pragma unroll
                for (int j = 0; j < 4; ++j) if (j < cnt) acc8(ra[j]);
            }
            if (t + 1 < nb) {
#pragma unroll
                for (int j = 0; j < 4; ++j) ra[j] = rb[j];
            }
        }

        float cdeg = (node < NN) ? (float)deg : 1.f;
        float rc = 1.0f / cdeg;
        float var[8];
#pragma unroll
        for (int i = 0; i < 8; ++i) {
            float mean = s[i] * rc;
            var[i] = fmaxf(q[i] * rc - mean * mean, 0.f);
            if (node >= NN) { mx[i] = 0.f; var[i] = 0.f; }
        }
        // f32 stats (for the VALU g=1 GEMM): [k][n] stride 34, cols 0..31
#pragma unroll
        for (int i = 0; i < 8; ++i) {
            Af32[(f0 + i) * 34 + m] = s[i];
            Af32[(64 + f0 + i) * 34 + m] = mx[i];
            Af32[(128 + f0 + i) * 34 + m] = var[i];
        }
        // bf16-hi stats (for the MFMA g=0,2 GEMM): [m][k] pitch 200
        uint4 hv;
        hv.x = pk(s[0], s[1]); hv.y = pk(s[2], s[3]);
        hv.z = pk(s[4], s[5]); hv.w = pk(s[6], s[7]);
        *(uint4*)&Ag[m * 200 + f0] = hv;
        hv.x = pk(mx[0], mx[1]); hv.y = pk(mx[2], mx[3]);
        hv.z = pk(mx[4], mx[5]); hv.w = pk(mx[6], mx[7]);
        *(uint4*)&Ag[m * 200 + 64 + f0] = hv;
        hv.x = pk(var[0], var[1]); hv.y = pk(var[2], var[3]);
        hv.z = pk(var[4], var[5]); hv.w = pk(var[6], var[7]);
        *(uint4*)&Ag[m * 200 + 128 + f0] = hv;
        if (l8 == 0) DEGV(m) = cdeg;
    }
    __syncthreads();

    // ---- load MFMA A fragments (then Ag is dead; hsf overlays it) ----
    const int ln = tid & 63, wvi = tid >> 6;
    const int quad = ln >> 4, l16 = ln & 15;
    const int mtile = wvi >> 1;          // 0..1
    const int nt0 = (wvi & 1) * 2;       // ntiles nt0, nt0+1

    const ushort* Arow = Ag + (mtile * 16 + l16) * 200 + quad * 8;
    short8 afh[6];
    afh[0] = *(const short8*)(Arow + 0);    // s    k 0..31
    afh[1] = *(const short8*)(Arow + 32);   // s    k 32..63
    afh[2] = *(const short8*)(Arow + 64);   // max  k 0..31
    afh[3] = *(const short8*)(Arow + 96);   // max  k 32..63
    afh[4] = *(const short8*)(Arow + 128);  // var  k 0..31
    afh[5] = *(const short8*)(Arow + 160);  // var  k 32..63
    __syncthreads();   // all frag loads done -> hsf region free

    // ---- MFMA: g=0 and g=2 chunks, bf16-hi ----
    floatx4 accA[2][2], accB[2][2];
#pragma unroll
    for (int gi = 0; gi < 2; ++gi)
#pragma unroll
        for (int n = 0; n < 2; ++n) {
            accA[gi][n] = (floatx4){0.f, 0.f, 0.f, 0.f};
            accB[gi][n] = (floatx4){0.f, 0.f, 0.f, 0.f};
        }
#pragma unroll
    for (int gi = 0; gi < 2; ++gi) {
        const int g = gi * 2;
#pragma unroll
        for (int kb = 0; kb < 8; ++kb) {
            const int am = (kb < 4) ? kb : ((kb < 6) ? (kb - 4) : (kb - 2));
            const int boff = (((g * 8 + kb) * 4 + nt0) * 512) + ln * 8;
            short8 bh0 = *(const short8*)(Wbh + boff);
            short8 bh1 = *(const short8*)(Wbh + boff + 512);
            if (kb == 4 || kb == 5) {
                accB[gi][0] = __builtin_amdgcn_mfma_f32_16x16x32_bf16(afh[am], bh0, accB[gi][0], 0, 0, 0);
                accB[gi][1] = __builtin_amdgcn_mfma_f32_16x16x32_bf16(afh[am], bh1, accB[gi][1], 0, 0, 0);
            } else {
                accA[gi][0] = __builtin_amdgcn_mfma_f32_16x16x32_bf16(afh[am], bh0, accA[gi][0], 0, 0, 0);
                accA[gi][1] = __builtin_amdgcn_mfma_f32_16x16x32_bf16(afh[am], bh1, accA[gi][1], 0, 0, 0);
            }
        }
    }
    // MFMA partial (scales for g=0: 1 and 1/c; g=2: D/c and D/c^2) -> hsf[n][m]
#pragma unroll
    for (int r = 0; r < 4; ++r) {
        int m = mtile * 16 + quad * 4 + r;
        float dg = DEGV(m), rcd = 1.f / dg;
        float cA2 = DELTA_F * rcd;
        float cB2 = DELTA_F * rcd * rcd;
#pragma unroll
        for (int nt = 0; nt < 2; ++nt) {
            int n = (nt0 + nt) * 16 + l16;
            hsf[n * 34 + m] = accA[0][nt][r] + cA2 * accA[1][nt][r]
                            + rcd * accB[0][nt][r] + cB2 * accB[1][nt][r];
        }
    }

    // ---- f32 VALU GEMM for g=1 chunk (amplified by cnt/DELTA) ----
    const int tx = tid & 15, ty = tid >> 4;
    const int o0 = tx * 4, n0 = ty * 2;
    const float2* const Af2 = (const float2*)Af32;   // stride 17 float2

    float A1[8], B1[8];
#pragma unroll
    for (int i = 0; i < 8; ++i) { A1[i] = 0.f; B1[i] = 0.f; }
#pragma unroll 4
    for (int k = 0; k < 128; ++k) {          // s rows(0..63) + max rows(64..127)
        float2 a = Af2[k * 17 + ty];
        const float4 w = *(const float4*)(Wt1 + k * 64 + o0);
        A1[0] += a.x * w.x; A1[1] += a.x * w.y; A1[2] += a.x * w.z; A1[3] += a.x * w.w;
        A1[4] += a.y * w.x; A1[5] += a.y * w.y; A1[6] += a.y * w.z; A1[7] += a.y * w.w;
    }
#pragma unroll 4
    for (int k = 0; k < 64; ++k) {           // var rows x W rows 192..255
        float2 a = Af2[(128 + k) * 17 + ty];
        const float4 w = *(const float4*)(Wt1 + (192 + k) * 64 + o0);
        A1[0] += a.x * w.x; A1[1] += a.x * w.y; A1[2] += a.x * w.z; A1[3] += a.x * w.w;
        A1[4] += a.y * w.x; A1[5] += a.y * w.y; A1[6] += a.y * w.z; A1[7] += a.y * w.w;
    }
#pragma unroll 4
    for (int k = 0; k < 64; ++k) {           // mean fold: s rows x W rows 128..191
        float2 a = Af2[k * 17 + ty];
        const float4 w = *(const float4*)(Wt1 + (128 + k) * 64 + o0);
        B1[0] += a.x * w.x; B1[1] += a.x * w.y; B1[2] += a.x * w.z; B1[3] += a.x * w.w;
        B1[4] += a.y * w.x; B1[5] += a.y * w.y; B1[6] += a.y * w.z; B1[7] += a.y * w.w;
    }
    __syncthreads();   // all MFMA partials in hsf

    // ---- combine: h = partial + (c/D)*A1 + (1/D)*B1 + x + bias ----
#pragma unroll
    for (int ni = 0; ni < 2; ++ni) {
        int n = n0 + ni;
        int node = node0 + n;
        float dg = DEGV(n);
        float cA1 = dg * (1.0f / DELTA_F);
        const float cB1 = (1.0f / DELTA_F);
        float xa4[4] = {0.f, 0.f, 0.f, 0.f};
        if (node < NN) {
            ushort4 hx = *(const ushort4*)(XH + (size_t)node * DD + o0);
            xa4[0] = bu2f(hx.x); xa4[1] = bu2f(hx.y);
            xa4[2] = bu2f(hx.z); xa4[3] = bu2f(hx.w);
        }
#pragma unroll
        for (int oi = 0; oi < 4; ++oi) {
            int idx = (o0 + oi) * 34 + n;
            hsf[idx] = hsf[idx] + cA1 * A1[ni * 4 + oi] + cB1 * B1[ni * 4 + oi]
                     + xa4[oi] + MBIAS(o0 + oi);
        }
    }
    __syncthreads();

    // ---- Lin1 (f32): stream W1t from global, h-pairs from LDS ----
    const float2* const hs2 = (const float2*)hsf;
    float l1[8];
#pragma unroll
    for (int i = 0; i < 8; ++i) l1[i] = 0.f;
#pragma unroll 4
    for (int j = 0; j < 64; ++j) {
        float2 a = hs2[j * 17 + ty];
        const float4 wv4 = *(const float4*)(W1t + j * 64 + o0);
        l1[0] += a.x * wv4.x; l1[1] += a.x * wv4.y; l1[2] += a.x * wv4.z; l1[3] += a.x * wv4.w;
        l1[4] += a.y * wv4.x; l1[5] += a.y * wv4.y; l1[6] += a.y * wv4.z; l1[7] += a.y * wv4.w;
    }
    __syncthreads();
#pragma unroll
    for (int ni = 0; ni < 2; ++ni)
#pragma unroll
        for (int oi = 0; oi < 4; ++oi)
            hsf[(o0 + oi) * 34 + n0 + ni] = fmaxf(l1[ni * 4 + oi] + B1V(o0 + oi), 0.f);
    __syncthreads();

    // ---- Lin2 + outer relu ----
    float l2[8];
#pragma unroll
    for (int i = 0; i < 8; ++i) l2[i] = 0.f;
#pragma unroll 4
    for (int j = 0; j < 64; ++j) {
        float2 a = hs2[j * 17 + ty];
        const float4 wv4 = *(const float4*)(W2t + j * 64 + o0);
        l2[0] += a.x * wv4.x; l2[1] += a.x * wv4.y; l2[2] += a.x * wv4.z; l2[3] += a.x * wv4.w;
        l2[4] += a.y * wv4.x; l2[5] += a.y * wv4.y; l2[6] += a.y * wv4.z; l2[7] += a.y * wv4.w;
    }
    __syncthreads();
#pragma unroll
    for (int ni = 0; ni < 2; ++ni) {
        int node = node0 + n0 + ni;
        float4 yv;
        yv.x = fmaxf(l2[ni * 4 + 0] + B2V(o0 + 0), 0.f);
        yv.y = fmaxf(l2[ni * 4 + 1] + B2V(o0 + 1), 0.f);
        yv.z = fmaxf(l2[ni * 4 + 2] + B2V(o0 + 2), 0.f);
        yv.w = fmaxf(l2[ni * 4 + 3] + B2V(o0 + 3), 0.f);
        if (node < NN) *(float4*)(Y + (size_t)node * DD + o0) = yv;
        hsf[(o0 + 0) * 34 + n0 + ni] = yv.x;
        hsf[(o0 + 1) * 34 + n0 + ni] = yv.y;
        hsf[(o0 + 2) * 34 + n0 + ni] = yv.z;
        hsf[(o0 + 3) * 34 + n0 + ni] = yv.w;
    }
    __syncthreads();

    // ---- BN partial sums ----
    if (tid < 64) {
        float s = 0.f, sq = 0.f;
        int lim = NN - node0;
        if (lim > 32) lim = 32;
        for (int n = 0; n < lim; ++n) {
            float v = hsf[tid * 34 + n];
            s += v;
            sq += v * v;
        }
        atomicAdd(&bnstat[tid], s);
        atomicAdd(&bnstat[64 + tid], sq);
    }
}

// ---------------- BN finalize+apply: bf16 table write (+ fused pool) ----------------
__global__ __launch_bounds__(256) void k_bnapply(
    const float* __restrict__ Y, const float* __restrict__ bs,
    const float* __restrict__ g, const float* __restrict__ b,
    ushort* __restrict__ XH,
    const int* __restrict__ batch, float* __restrict__ gpool, int do_pool) {
    __shared__ float sc[64], shf[64], pool[512];
    int tid = threadIdx.x;
    if (tid < 64) {
        float mean = bs[tid] * (1.f / NN);
        float var = fmaxf(bs[64 + tid] * (1.f / NN) - mean * mean, 0.f);
        float inv = rsqrtf(var + BN_EPS_F);
        float s = g[tid] * inv;
        sc[tid] = s;
        shf[tid] = b[tid] - mean * s;
    }
    __syncthreads();
    int i = blockIdx.x * 256 + tid;  // float4 index
    int n = i >> 4, fq = (i & 15) * 4;
    float4 r = make_float4(0.f, 0.f, 0.f, 0.f);
    bool valid = i < NN * 16;
    if (valid) {
        float4 y = *(const float4*)(Y + (size_t)i * 4);
        r.x = y.x * sc[fq + 0] + shf[fq + 0];
        r.y = y.y * sc[fq + 1] + shf[fq + 1];
        r.z = y.z * sc[fq + 2] + shf[fq + 2];
        r.w = y.w * sc[fq + 3] + shf[fq + 3];
        ushort4 h;
        h.x = f2bu(r.x); h.y = f2bu(r.y); h.z = f2bu(r.z); h.w = f2bu(r.w);
        *(ushort4*)(XH + (size_t)i * 4) = h;
    }
    if (do_pool) {
        int nfirst = blockIdx.x * 16;
        int nlast = nfirst + 15;
        if (nlast >= NN) nlast = NN - 1;
        int gmin = batch[nfirst], gmax = batch[nlast];
        int span = gmax - gmin + 1;
        if (span <= 8) {
            for (int j = tid; j < span * 64; j += 256) pool[j] = 0.f;
            __syncthreads();
            if (valid) {
                int gb = batch[n] - gmin;
                atomicAdd(&pool[gb * 64 + fq + 0], r.x);
                atomicAdd(&pool[gb * 64 + fq + 1], r.y);
                atomicAdd(&pool[gb * 64 + fq + 2], r.z);
                atomicAdd(&pool[gb * 64 + fq + 3], r.w);
            }
            __syncthreads();
            for (int j = tid; j < span * 64; j += 256)
                atomicAdd(&gpool[(size_t)(gmin + (j >> 6)) * 64 + (j & 63)], pool[j]);
        } else {
            if (valid) {
                float* gp = gpool + (size_t)batch[n] * DD + fq;
                atomicAdd(gp + 0, r.x);
                atomicAdd(gp + 1, r.y);
                atomicAdd(gp + 2, r.z);
                atomicAdd(gp + 3, r.w);
            }
        }
    }
}

// ---------------- head: fc1+relu, fc2, log_softmax ----------------
__global__ __launch_bounds__(256) void k_head(const float* __restrict__ gpool,
                                              const float* __restrict__ fc1W, const float* __restrict__ fc1b,
                                              const float* __restrict__ fc2W, const float* __restrict__ fc2b,
                                              float* __restrict__ out) {
    __shared__ float sh[12576];
    float* const gs = sh;
    float* const w1t = sh + 4096;
    float* const z1s = sh + 8256;
    float* const b1s = sh + 12416;
    float* const b2s = sh + 12480;
    float* const w2t = sh;
    float* const z2s = sh + 4096;

    int tid = threadIdx.x;
    for (int i = tid; i < 4096; i += 256) {
        gs[i] = gpool[i];
        int o = i >> 6, j = i & 63;
        w1t[j * 65 + o] = fc1W[i];
    }
    if (tid < 64) b1s[tid] = fc1b[tid];
    if (tid < 32) b2s[tid] = fc2b[tid];
    __syncthreads();
    {
        int tx = tid & 15, ty = tid >> 4, o0 = tx * 4, g0 = ty * 4;
        float acc[16];
#pragma unroll
        for (int i = 0; i < 16; ++i) acc[i] = 0.f;
        for (int j = 0; j < 64; ++j) {
            float w0 = w1t[j * 65 + o0 + 0], w1 = w1t[j * 65 + o0 + 1];
            float w2 = w1t[j * 65 + o0 + 2], w3 = w1t[j * 65 + o0 + 3];
#pragma unroll
            for (int gi = 0; gi < 4; ++gi) {
                float a = gs[(g0 + gi) * 64 + j];
                acc[gi * 4 + 0] += a * w0; acc[gi * 4 + 1] += a * w1;
                acc[gi * 4 + 2] += a * w2; acc[gi * 4 + 3] += a * w3;
            }
        }
        __syncthreads();
#pragma unroll
        for (int gi = 0; gi < 4; ++gi)
#pragma unroll
            for (int oi = 0; oi < 4; ++oi)
                z1s[(g0 + gi) * 65 + o0 + oi] = fmaxf(acc[gi * 4 + oi] + b1s[o0 + oi], 0.f);
    }
    for (int i = tid; i < 2048; i += 256) {
        int o = i >> 6, j = i & 63;
        w2t[j * 33 + o] = fc2W[i];
    }
    __syncthreads();
    {
        int tx = tid & 7, ty = tid >> 3, o0 = tx * 4, g0 = ty * 2;
        float acc[8];
#pragma unroll
        for (int i = 0; i < 8; ++i) acc[i] = 0.f;
        for (int j = 0; j < 64; ++j) {
            float w0 = w2t[j * 33 + o0 + 0], w1 = w2t[j * 33 + o0 + 1];
            float w2 = w2t[j * 33 + o0 + 2], w3 = w2t[j * 33 + o0 + 3];
            float a0 = z1s[(g0 + 0) * 65 + j];
            float a1 = z1s[(g0 + 1) * 65 + j];
            acc[0] += a0 * w0; acc[1] += a0 * w1; acc[2] += a0 * w2; acc[3] += a0 * w3;
            acc[4] += a1 * w0; acc[5] += a1 * w1; acc[6] += a1 * w2; acc[7] += a1 * w3;
        }
#pragma unroll
        for (int gi = 0; gi < 2; ++gi)
#pragma unroll
            for (int oi = 0; oi < 4; ++oi)
                z2s[(g0 + gi) * 33 + o0 + oi] = acc[gi * 4 + oi] + b2s[o0 + oi];
    }
    __syncthreads();
    if (tid < 64) {
        float m = -3.402823466e38f;
        for (int c = 0; c < DOUT; ++c) m = fmaxf(m, z2s[tid * 33 + c]);
        float s = 0.f;
        for (int c = 0; c < DOUT; ++c) s += expf(z2s[tid * 33 + c] - m);
        float lse = m + logf(s);
        for (int c = 0; c < DOUT; ++c)
            out[tid * DOUT + c] = z2s[tid * 33 + c] - lse;
    }
}

extern "C" void kernel_launch(void* const* d_in, const int* in_sizes, int n_in,
                              void* d_out, int out_size, void* d_ws, size_t ws_size,
                              hipStream_t stream) {
    const float* x = (const float*)d_in[0];
    const int* ei = (const int*)d_in[1];
    const int* src = ei;
    const int* dst = ei + NE;
    const int* batch = (const int*)d_in[2];
    const float *mlpW[3], *mlpB[3], *w1[3], *bb1[3], *w2[3], *bb2[3], *bng[3], *bnb[3];
    for (int l = 0; l < 3; ++l) {
        mlpW[l] = (const float*)d_in[3 + 6 * l];
        mlpB[l] = (const float*)d_in[4 + 6 * l];
        w1[l]   = (const float*)d_in[5 + 6 * l];
        bb1[l]  = (const float*)d_in[6 + 6 * l];
        w2[l]   = (const float*)d_in[7 + 6 * l];
        bb2[l]  = (const float*)d_in[8 + 6 * l];
        bng[l]  = (const float*)d_in[21 + 2 * l];
        bnb[l]  = (const float*)d_in[22 + 2 * l];
    }
    const float* fc1W = (const float*)d_in[27];
    const float* fc1b = (const float*)d_in[28];
    const float* fc2W = (const float*)d_in[29];
    const float* fc2b = (const float*)d_in[30];
    float* out = (float*)d_out;

    char* ws = (char*)d_ws;
    size_t off = 0;
    auto alloc = [&](size_t bytes) -> void* {
        void* p = ws + off;
        off = (off + bytes + 511) & ~(size_t)511;
        return p;
    };
    int* counts    = (int*)alloc((size_t)NN * 4);
    int* row_ptr   = (int*)alloc((size_t)(NN + 1) * 4);
    int* rank      = (int*)alloc((size_t)NE * 4);
    int* blockSums = (int*)alloc(256 * 4);
    int* blockBase = (int*)alloc(256 * 4);
    int* csr_src   = (int*)alloc((size_t)NE * 4);
    float* Yb      = (float*)alloc((size_t)NN * DD * 4);
    ushort* XH     = (ushort*)alloc((size_t)NN * DD * 2);
    ushort* Wb     = (ushort*)alloc((size_t)3 * 49152 * 2);
    float* Wt1     = (float*)alloc((size_t)3 * 16384 * 4);
    float* Wsm     = (float*)alloc((size_t)6 * 4096 * 4);
    float* bnstat  = (float*)alloc(384 * 4);
    float* gpool   = (float*)alloc((size_t)NGRAPH * DD * 4);
    (void)ws_size; (void)in_sizes; (void)n_in; (void)out_size;

    k_init<<<196, 256, 0, stream>>>(counts, bnstat, gpool);
    k_rank<<<6250, 256, 0, stream>>>(dst, counts, rank);
    k_scan_a<<<196, 256, 0, stream>>>(counts, blockSums);
    k_scan_b<<<1, 256, 0, stream>>>(blockSums, blockBase);
    k_scan_c<<<196, 256, 0, stream>>>(counts, blockBase, row_ptr);
    k_place<<<6250, 256, 0, stream>>>(src, dst, rank, row_ptr, csr_src);
    k_wprep<<<864, 256, 0, stream>>>(mlpW[0], mlpW[1], mlpW[2],
                                     w1[0], w2[0], w1[1], w2[1], w1[2], w2[2],
                                     Wb, Wt1, Wsm);
    k_x2h<<<3125, 256, 0, stream>>>(x, XH);

    for (int l = 0; l < 3; ++l) {
        k_fused<<<1563, 256, 0, stream>>>(XH, row_ptr, csr_src,
                                          Wb + (size_t)l * 49152,
                                          Wt1 + (size_t)l * 16384,
                                          mlpB[l],
                                          Wsm + (size_t)(2 * l) * 4096, bb1[l],
                                          Wsm + (size_t)(2 * l + 1) * 4096, bb2[l],
                                          Yb, bnstat + l * 128);
        k_bnapply<<<3125, 256, 0, stream>>>(Yb, bnstat + l * 128, bng[l], bnb[l],
                                            XH, batch, gpool, (l == 2) ? 1 : 0);
    }
    k_head<<<1, 256, 0, stream>>>(gpool, fc1W, fc1b, fc2W, fc2b, out);
}